// Round 10
// baseline (467.107 us; speedup 1.0000x reference)
//
#include <hip/hip_runtime.h>

// Soft-DTW, B=64, L=1024, C=64, gamma=1.
// R6 skeleton (PROVEN: absmax 0.0): 16 row-bands of 64 rows; wave = band;
// lane = row; 4 waves/block, 4 blocks/batch (256 blocks = 256 CUs, 1 wave/SIMD).
// Band handoff: LDS Hb (float2) chunk-granular in-block; global HX + agent
// flags across blocks. DP in EXPONENTIAL domain: V = 2^(-R) = u * 2^S,
// u in [0.5,1), S int32. BIG == (u=0.5, S=-2^24) ~ 0.
// R10: ldexp/frexp via BIT OPS (no ocml, no asm, no branches, no trans):
//   ldexp(u,k): k=max(k,-126); f = int_as_float(float_as_int(u) + (k<<23))
//   frexp(un):  e=(ub>>23)&255; mant=(ub&0x7fffff)|0x3f000000
//   S' = Sm - (di+126) + e   (bias folded into dic at D-prep, off-chain)
// ~29 VALU ops/step, chain ~15-20cy -> issue-bound ~60-90 cy/step (vs 241).

typedef unsigned short ushort_t;
typedef __attribute__((ext_vector_type(8))) short short8;
typedef __attribute__((ext_vector_type(4))) float f32x4;
typedef __attribute__((ext_vector_type(4))) unsigned short ushort4v;

constexpr int B_ = 64, L_ = 1024, C_ = 64;
constexpr int DSTRW = 129;   // u32 row stride

#define BIGS (-(1 << 24))
#define INV_LN2 1.44269504088896340736f
#define LN2F 0.69314718055994530942f

static __device__ __forceinline__ ushort_t f2bf(float f) {
  unsigned u = __builtin_bit_cast(unsigned, f);
  unsigned r = (u + 0x7fffu + ((u >> 16) & 1u)) >> 16;
  return (ushort_t)r;
}
// lane i <- lane i-1; lane 0 <- old[0]   (wave_shr:1)
static __device__ __forceinline__ float dpp_shr1(float old, float src) {
  return __builtin_bit_cast(float, __builtin_amdgcn_update_dpp(
      __builtin_bit_cast(int, old), __builtin_bit_cast(int, src), 0x138, 0xF, 0xF, false));
}
static __device__ __forceinline__ int dpp_shr1_i(int old, int src) {
  return __builtin_amdgcn_update_dpp(old, src, 0x138, 0xF, 0xF, false);
}
// lane i <- lane i+1 (wave_shl:1, lane 63 keeps old)
static __device__ __forceinline__ float dpp_shl1(float v) {
  return __builtin_bit_cast(float, __builtin_amdgcn_update_dpp(
      __builtin_bit_cast(int, v), __builtin_bit_cast(int, v), 0x130, 0xF, 0xF, false));
}
static __device__ __forceinline__ int dpp_shl1_i(int v) {
  return __builtin_amdgcn_update_dpp(v, v, 0x130, 0xF, 0xF, false);
}
static __device__ __forceinline__ int imax3(int a, int b, int c) {
  int m = a > b ? a : b; return c > m ? c : m;
}
// exact bit-ldexp for u in [0.5,1), k <= 0 (k <= -126 -> ~0)
static __device__ __forceinline__ float bit_ldexp(float u, int k) {
  k = k > -126 ? k : -126;
  return __int_as_float(__float_as_int(u) + (int)((unsigned)k << 23));
}

// Pass 1: bf16 conversion (RNE), norms scaled by 1/ln2 with +0.25 baked
// (x2+y2 then carries the +0.5 used for the round-half int split), zero flags.
__global__ __launch_bounds__(256) void prep_kernel(
    const float* __restrict__ x, const float* __restrict__ y,
    ushort_t* __restrict__ xb, ushort_t* __restrict__ yb,
    float* __restrict__ x2, float* __restrict__ y2, int* __restrict__ flagsG)
{
  if (blockIdx.x == 0 && threadIdx.x < 192) flagsG[threadIdx.x] = 0;
  const int lane = threadIdx.x & 63;
  const int sub = lane >> 4;
  const int cg  = lane & 15;
  const int wv = (blockIdx.x * blockDim.x + threadIdx.x) >> 6;
  const int nw = (gridDim.x * blockDim.x) >> 6;
  const int totalGroups = (2 * B_ * L_) >> 2;
  for (int g = wv; g < totalGroups; g += nw) {
    int r = g * 4 + sub;
    const float* src; ushort_t* dst; float* nrm;
    if (r < B_ * L_) { src = x; dst = xb; nrm = x2; }
    else             { r -= B_ * L_; src = y; dst = yb; nrm = y2; }
    const float4 v = *(const float4*)(src + (size_t)r * C_ + cg * 4);
    ushort4v p;
    p.x = f2bf(v.x); p.y = f2bf(v.y); p.z = f2bf(v.z); p.w = f2bf(v.w);
    *(ushort4v*)(dst + (size_t)r * C_ + cg * 4) = p;
    float s = v.x*v.x + v.y*v.y + v.z*v.z + v.w*v.w;
    s += __shfl_xor(s, 1); s += __shfl_xor(s, 2);
    s += __shfl_xor(s, 4); s += __shfl_xor(s, 8);
    if (cg == 0) nrm[r] = s * INV_LN2 + 0.25f;
  }
}

// One 64-step chunk, exp-domain. HDST: 0 = LDS Hb, 1 = global HX, 2 = none.
template<int HDST, bool FIRST>
static __device__ __forceinline__ void dp_chunk(
    const int t, const int lane,
    float& cur_u, int& cur_S, float& dgp_u, int& dgp_S,
    float hv_u, int hv_S, const float zu, const int zS,
    const unsigned* __restrict__ DtLane,
    float2* __restrict__ HbDst, float2* __restrict__ HXB)
{
  const unsigned* pw = DtLane + ((t & 1) << 6);
  const int cb = (t << 6) - 63;          // lane-63 col at local step u is cb+u
  unsigned d0=pw[0],d1=pw[1],d2=pw[2],d3=pw[3],d4=pw[4],d5=pw[5],d6=pw[6],d7=pw[7];

  auto step = [&](unsigned dw, int u) {
    float up_u = dpp_shr1(hv_u, cur_u);  // lane0 <- external top value
    int   up_S = dpp_shr1_i(hv_S, cur_S);
    hv_u = dpp_shl1(hv_u);
    hv_S = dpp_shl1_i(hv_S);
    float p = (float)__builtin_bit_cast(_Float16, (unsigned short)(dw & 0xffffu));
    int dic = (int)(dw >> 16) + 126;     // di + 126 (exp-bias fold), off-chain
    float dg_u = dgp_u, lf_u = cur_u;
    int   dg_S = dgp_S, lf_S = cur_S;
    if constexpr (FIRST) {
      const bool a0 = (u == lane);       // col == 0: left boundary
      dg_u = a0 ? zu : dg_u;   dg_S = a0 ? zS : dg_S;
      lf_u = a0 ? 0.5f : lf_u; lf_S = a0 ? BIGS : lf_S;
    }
    int Sm = imax3(up_S, dg_S, lf_S);
    float f1 = bit_ldexp(up_u, up_S - Sm);
    float f2 = bit_ldexp(dg_u, dg_S - Sm);
    float f3 = bit_ldexp(lf_u, lf_S - Sm);
    float un = ((f1 + f2) + f3) * p;     // in [0.35, 4.3] always (max input k=0)
    int ub = __float_as_int(un);
    int Sn = Sm - dic + ((ub >> 23) & 0xff);
    float mant = __int_as_float((ub & 0x007fffff) | 0x3f000000);
    dgp_u = up_u; dgp_S = up_S;
    const bool wr = FIRST ? (u >= lane) : true;
    if (wr) { cur_u = mant; cur_S = Sn; }
    if constexpr (!FIRST && HDST != 2) {
      if (lane == 63) {
        float2 pr; pr.x = mant; pr.y = __int_as_float(Sn);
        if constexpr (HDST == 0) HbDst[cb + u] = pr;
        else                     HXB[cb + u] = pr;
      }
    }
  };

  #pragma unroll 1
  for (int g = 0; g < 8; ++g) {
    unsigned n0=0,n1=0,n2=0,n3=0,n4=0,n5=0,n6=0,n7=0;
    if (g < 7) {
      const unsigned* np = pw + ((g + 1) << 3);
      n0=np[0]; n1=np[1]; n2=np[2]; n3=np[3]; n4=np[4]; n5=np[5]; n6=np[6]; n7=np[7];
    }
    const int u0 = g << 3;
    step(d0, u0+0); step(d1, u0+1); step(d2, u0+2); step(d3, u0+3);
    step(d4, u0+4); step(d5, u0+5); step(d6, u0+6); step(d7, u0+7);
    d0=n0; d1=n1; d2=n2; d3=n3; d4=n4; d5=n5; d6=n6; d7=n7;
  }
  if constexpr (FIRST && HDST != 2) {
    // chunk 0: lane 63's only valid col is 0 (reached at u=63)
    if (lane == 63) {
      float2 pr; pr.x = cur_u; pr.y = __int_as_float(cur_S);
      if constexpr (HDST == 0) HbDst[0] = pr; else HXB[0] = pr;
    }
  }
}

// Tail: 63 skew-drain steps, c = 1024 + u - lane, valid iff u < lane.
template<int HDST>
static __device__ __forceinline__ void dp_tail(
    const int lane, float& cur_u, int& cur_S, float& dgp_u, int& dgp_S,
    const unsigned* __restrict__ DtLane,
    float2* __restrict__ HbDst, float2* __restrict__ HXB)
{
  const unsigned* pw = DtLane;           // chunk 16 -> slots 0..63
  #pragma unroll 1
  for (int g = 0; g < 8; ++g) {
    unsigned w0=pw[g*8],w1=pw[g*8+1],w2=pw[g*8+2],w3=pw[g*8+3],
             w4=pw[g*8+4],w5=pw[g*8+5],w6=pw[g*8+6],w7=pw[g*8+7];
    #pragma unroll
    for (int k = 0; k < 8; ++k) {
      const int u = g * 8 + k;
      unsigned dw = (k==0)?w0:(k==1)?w1:(k==2)?w2:(k==3)?w3:(k==4)?w4:(k==5)?w5:(k==6)?w6:w7;
      float up_u = dpp_shr1(0.5f, cur_u);
      int   up_S = dpp_shr1_i(BIGS, cur_S);
      float p = (float)__builtin_bit_cast(_Float16, (unsigned short)(dw & 0xffffu));
      int dic = (int)(dw >> 16) + 126;
      int Sm = imax3(up_S, dgp_S, cur_S);
      float f1 = bit_ldexp(up_u, up_S - Sm);
      float f2 = bit_ldexp(dgp_u, dgp_S - Sm);
      float f3 = bit_ldexp(cur_u, cur_S - Sm);
      float un = ((f1 + f2) + f3) * p;
      int ub = __float_as_int(un);
      int Sn = Sm - dic + ((ub >> 23) & 0xff);
      float mant = __int_as_float((ub & 0x007fffff) | 0x3f000000);
      dgp_u = up_u; dgp_S = up_S;
      if (u < lane) {
        cur_u = mant; cur_S = Sn;
        if (lane == 63) {
          float2 pr; pr.x = mant; pr.y = __int_as_float(Sn);
          if constexpr (HDST == 0) HbDst[961 + u] = pr;
          else if constexpr (HDST == 1) HXB[961 + u] = pr;
        }
      }
    }
  }
}

static __device__ __forceinline__ void spin_lds(int* f, int v) {
  int k = 0;
  while (__hip_atomic_load(f, __ATOMIC_ACQUIRE, __HIP_MEMORY_SCOPE_WORKGROUP) < v) {
    __builtin_amdgcn_s_sleep(1);
    if (++k > (1 << 26)) break;
  }
}
static __device__ __forceinline__ void spin_glb(int* f, int v) {
  int k = 0;
  while (__hip_atomic_load(f, __ATOMIC_ACQUIRE, __HIP_MEMORY_SCOPE_AGENT) < v) {
    __builtin_amdgcn_s_sleep(2);
    if (++k > (1 << 26)) break;
  }
}

// HSRC: 0 = BIG top (band 0), 1 = LDS Hb, 2 = global HX.
// HDST: 0 = LDS Hb, 1 = global HX, 2 = none (band 15).
template<int HSRC, int HDST>
static __device__ __forceinline__ void run_band(
    const ushort_t* __restrict__ xbB, const ushort_t* __restrict__ ybB,
    const float* __restrict__ x2B, const float* __restrict__ y2B,
    const float2* __restrict__ HXin, float2* __restrict__ HXout,
    int* __restrict__ fGin, int* __restrict__ fGout,
    unsigned* __restrict__ Dtw, const float2* __restrict__ HbSrc,
    float2* __restrict__ HbDst, int* __restrict__ cin, int* __restrict__ cout,
    const int lane, const int W, float* __restrict__ outp)
{
  const int m = lane & 15, q = lane >> 4;
  const int i0 = W * 64;

  short8 af[4][2];
  #pragma unroll
  for (int mt = 0; mt < 4; ++mt)
    #pragma unroll
    for (int ks = 0; ks < 2; ++ks)
      af[mt][ks] = *(const short8*)(xbB + (size_t)(i0 + mt * 16 + m) * C_ + ks * 32 + q * 8);
  f32x4 x2q[4];
  #pragma unroll
  for (int mt = 0; mt < 4; ++mt) x2q[mt] = *(const f32x4*)(x2B + i0 + mt * 16 + q * 4);

  short8 bfr0[4], bfr1[4];
  f32x4 y2r = {0.f, 0.f, 0.f, 0.f};
  auto load_bfr = [&](int tc) {
    const ushort_t* yb0 = ybB + (size_t)tc * 64 * C_;
    #pragma unroll
    for (int nt = 0; nt < 4; ++nt) {
      bfr0[nt] = *(const short8*)(yb0 + (size_t)(nt * 16 + m) * C_ + q * 8);
      bfr1[nt] = *(const short8*)(yb0 + (size_t)(nt * 16 + m) * C_ + 32 + q * 8);
      y2r[nt] = y2B[tc * 64 + nt * 16 + m];
    }
  };
  // Gram tile tc -> skewed LDS u32 cells: row r, slot (col+r)&127,
  // cell = (di<<16) | f16(p),  p = 2^(di - D2) in (0.707, 1.415)
  auto gram = [&](int tc) {
    const int cb = tc * 64;
    #pragma unroll
    for (int mt = 0; mt < 4; ++mt) {
      const int r0 = mt * 16 + q * 4;
      #pragma unroll
      for (int nt = 0; nt < 4; ++nt) {
        f32x4 acc = {0.f, 0.f, 0.f, 0.f};
        acc = __builtin_amdgcn_mfma_f32_16x16x32_bf16(af[mt][0], bfr0[nt], acc, 0, 0, 0);
        acc = __builtin_amdgcn_mfma_f32_16x16x32_bf16(af[mt][1], bfr1[nt], acc, 0, 0, 0);
        const float y2v = y2r[nt];
        const int cs = cb + nt * 16 + m + r0;
        #pragma unroll
        for (int reg = 0; reg < 4; ++reg) {
          float d = fmaf(acc[reg], -2.f * INV_LN2, x2q[mt][reg] + y2v); // D2 + 0.5
          d = fmaxf(d, 0.5f);                               // guard: di >= 0
          int di = (int)d;                                  // trunc = round(D2)
          float pe = (float)di + 0.5f - d;                  // in (-0.5, 0.5]
          float p = __builtin_amdgcn_exp2f(pe);
          unsigned short hb = __builtin_bit_cast(unsigned short, (_Float16)p);
          Dtw[(r0 + reg) * DSTRW + ((cs + reg) & 127)] = ((unsigned)di << 16) | (unsigned)hb;
        }
      }
    }
  };
  auto signal = [&](int v) {
    if constexpr (HDST == 0) {
      if (lane == 0) __hip_atomic_store(cout, v, __ATOMIC_RELEASE, __HIP_MEMORY_SCOPE_WORKGROUP);
    } else if constexpr (HDST == 1) {
      if (lane == 0) __hip_atomic_store(fGout, v, __ATOMIC_RELEASE, __HIP_MEMORY_SCOPE_AGENT);
    }
  };

  float cur_u = 0.5f, dgp_u = 0.5f;
  int cur_S = BIGS, dgp_S = BIGS;
  const float zu = 0.5f;                                   // V(R=0)=1 = 0.5*2^1
  const int   zS = (W == 0 && lane == 0) ? 1 : BIGS;
  const unsigned* DtLane = Dtw + lane * DSTRW;

  load_bfr(0);
  gram(0);

  #pragma unroll 1
  for (int t = 0; t < 16; ++t) {
    if (t < 15) load_bfr(t + 1);
    float hv_u; int hv_S;
    if constexpr (HSRC == 0) {
      hv_u = 0.5f; hv_S = BIGS;
    } else if constexpr (HSRC == 1) {
      spin_lds(cin, t + 1);
      float2 pr = HbSrc[(t << 6) + lane];
      hv_u = pr.x; hv_S = __float_as_int(pr.y);
    } else {
      spin_glb(fGin, t + 1);
      float2 pr = HXin[(t << 6) + lane];
      hv_u = pr.x; hv_S = __float_as_int(pr.y);
    }
    if (t == 0)
      dp_chunk<HDST, true >(0, lane, cur_u, cur_S, dgp_u, dgp_S, hv_u, hv_S, zu, zS, DtLane, HbDst, HXout);
    else
      dp_chunk<HDST, false>(t, lane, cur_u, cur_S, dgp_u, dgp_S, hv_u, hv_S, zu, zS, DtLane, HbDst, HXout);
    signal(t);
    if (t < 15) gram(t + 1);
  }
  dp_tail<HDST>(lane, cur_u, cur_S, dgp_u, dgp_S, DtLane, HbDst, HXout);
  signal(16);
  if (W == 15 && lane == 63)
    *outp = (-(float)cur_S - __builtin_amdgcn_logf(cur_u)) * LN2F;  // R = -S - log2(u)
}

__global__ __launch_bounds__(256) void sdtw_kernel(
    const ushort_t* __restrict__ xb, const ushort_t* __restrict__ yb,
    const float* __restrict__ x2g, const float* __restrict__ y2g,
    float2* __restrict__ HXg, int* __restrict__ flagsG,
    float* __restrict__ out)
{
  // LDS: Dt 4*64*129*4 = 132096 ; Hb 3*1024*8 = 24576 ; cflag 16 => 156688 B
  __shared__ unsigned Dt[4][64 * DSTRW];
  __shared__ float2 Hb[3][1024];
  __shared__ int cflag[4];

  const int b = blockIdx.x & 63;       // blocks b, b+64, b+128, b+192: same XCD slot
  const int sub = blockIdx.x >> 6;     // 0..3 -> bands sub*4 .. sub*4+3
  const int w = threadIdx.x >> 6;
  const int lane = threadIdx.x & 63;
  const int W = sub * 4 + w;

  if (threadIdx.x < 4) cflag[threadIdx.x] = 0;
  __syncthreads();                     // only barrier in the kernel

  const ushort_t* xbB = xb + (size_t)b * L_ * C_;
  const ushort_t* ybB = yb + (size_t)b * L_ * C_;
  const float* x2B = x2g + b * L_;
  const float* y2B = y2g + b * L_;
  // boundary buffers: HXg[b][bnd][1024], bnd = 0,1,2 after bands 3,7,11
  const float2* HXin = HXg + ((size_t)b * 3 + (sub > 0 ? sub - 1 : 0)) * L_;
  float2* HXout      = HXg + ((size_t)b * 3 + (sub < 3 ? sub : 2)) * L_;
  int* fGin  = flagsG + b * 3 + (sub > 0 ? sub - 1 : 0);
  int* fGout = flagsG + b * 3 + (sub < 3 ? sub : 2);
  unsigned* Dtw = &Dt[w][0];
  const float2* HbSrc = (w > 0) ? &Hb[w - 1][0] : &Hb[0][0];
  float2* HbDst = (w < 3) ? &Hb[w][0] : &Hb[0][0];
  int* cin  = (w > 0) ? &cflag[w - 1] : &cflag[0];
  int* cout = (w < 3) ? &cflag[w] : &cflag[3];
  float* outp = out + b;

  if (sub == 0) {
    if (w == 0)      run_band<0, 0>(xbB, ybB, x2B, y2B, HXin, HXout, fGin, fGout, Dtw, HbSrc, HbDst, cin, cout, lane, W, outp);
    else if (w < 3)  run_band<1, 0>(xbB, ybB, x2B, y2B, HXin, HXout, fGin, fGout, Dtw, HbSrc, HbDst, cin, cout, lane, W, outp);
    else             run_band<1, 1>(xbB, ybB, x2B, y2B, HXin, HXout, fGin, fGout, Dtw, HbSrc, HbDst, cin, cout, lane, W, outp);
  } else if (sub < 3) {
    if (w == 0)      run_band<2, 0>(xbB, ybB, x2B, y2B, HXin, HXout, fGin, fGout, Dtw, HbSrc, HbDst, cin, cout, lane, W, outp);
    else if (w < 3)  run_band<1, 0>(xbB, ybB, x2B, y2B, HXin, HXout, fGin, fGout, Dtw, HbSrc, HbDst, cin, cout, lane, W, outp);
    else             run_band<1, 1>(xbB, ybB, x2B, y2B, HXin, HXout, fGin, fGout, Dtw, HbSrc, HbDst, cin, cout, lane, W, outp);
  } else {
    if (w == 0)      run_band<2, 0>(xbB, ybB, x2B, y2B, HXin, HXout, fGin, fGout, Dtw, HbSrc, HbDst, cin, cout, lane, W, outp);
    else if (w < 3)  run_band<1, 0>(xbB, ybB, x2B, y2B, HXin, HXout, fGin, fGout, Dtw, HbSrc, HbDst, cin, cout, lane, W, outp);
    else             run_band<1, 2>(xbB, ybB, x2B, y2B, HXin, HXout, fGin, fGout, Dtw, HbSrc, HbDst, cin, cout, lane, W, outp);
  }
}

extern "C" void kernel_launch(void* const* d_in, const int* in_sizes, int n_in,
                              void* d_out, int out_size, void* d_ws, size_t ws_size,
                              hipStream_t stream) {
  const float* x = (const float*)d_in[0];
  const float* y = (const float*)d_in[1];
  float* out = (float*)d_out;

  // ws: xb 8MB | yb 8MB | x2 256KB | y2 256KB | HX (float2) 1.5MB | flagsG 768B
  char* ws = (char*)d_ws;
  const size_t XB = (size_t)B_ * L_ * C_ * 2;
  const size_t NB = (size_t)B_ * L_ * 4;
  ushort_t* xb = (ushort_t*)ws;
  ushort_t* yb = (ushort_t*)(ws + XB);
  float* x2 = (float*)(ws + 2 * XB);
  float* y2 = (float*)(ws + 2 * XB + NB);
  float2* HX = (float2*)(ws + 2 * XB + 2 * NB);
  int* flagsG = (int*)(ws + 2 * XB + 2 * NB + (size_t)B_ * 3 * L_ * 8);

  prep_kernel<<<512, 256, 0, stream>>>(x, y, xb, yb, x2, y2, flagsG);
  sdtw_kernel<<<256, 256, 0, stream>>>(xb, yb, x2, y2, HX, flagsG, out);
}